// Round 6
// baseline (286.605 us; speedup 1.0000x reference)
//
#include <hip/hip_runtime.h>
#include <cmath>

// Round 6: attention restructure — 32 q-rows/wave (128-row blocks).
//  - K/V fragments read from LDS once per chunk, shared across both 16-row
//    subtiles (per-score LDS traffic 1.7x lower); chunks/barriers halve
//  - grid 1024 blocks fully resident (4/CU); jb in low bits of blockIdx with
//    m[s]+m[s^8]=15 pairing so each CU's resident blocks sum to equal work
// GEMM pipeline unchanged from round 5.
// B=4 T=2048 C=1024 H=16 hd=64.

typedef short short8 __attribute__((ext_vector_type(8)));
typedef short short4v __attribute__((ext_vector_type(4)));
typedef float f32x4 __attribute__((ext_vector_type(4)));

__device__ __forceinline__ short f2bf(float f) {
  unsigned u = __builtin_bit_cast(unsigned, f);
  u = (u + 0x7fffu + ((u >> 16) & 1u)) >> 16;   // RNE; inputs are finite
  return (short)u;
}

__device__ __forceinline__ float exp2_fast(float x) {
  float r;
  asm("v_exp_f32 %0, %1" : "=v"(r) : "v"(x));
  return r;
}

__device__ __forceinline__ void gld_lds16(const void* g, void* l) {
  __builtin_amdgcn_global_load_lds(
      (__attribute__((address_space(1))) void*)g,
      (__attribute__((address_space(3))) void*)l,
      16, 0, 0);
}

// ---------------- cast fp32 -> bf16 bits (4 elems/thread) ----------------
__global__ void cast_bf16_kernel(const float* __restrict__ in,
                                 short* __restrict__ out, int n4) {
  int i = blockIdx.x * blockDim.x + threadIdx.x;
  if (i < n4) {
    const float4 v = ((const float4*)in)[i];
    short4v o;
    o.x = f2bf(v.x); o.y = f2bf(v.y); o.z = f2bf(v.z); o.w = f2bf(v.w);
    ((short4v*)out)[i] = o;
  }
}

// ------------- transpose+cast: fp32 [R][C] -> bf16 [C][R] ----------------
__global__ void transpose_cast_kernel(const float* __restrict__ in,
                                      short* __restrict__ out, int R, int C) {
  __shared__ float tile[32][33];
  int c0 = blockIdx.x * 32, r0 = blockIdx.y * 32;
  int tx = threadIdx.x & 31, tg = threadIdx.x >> 5;
#pragma unroll
  for (int i = 0; i < 4; ++i) {
    int r = tg * 4 + i;
    tile[r][tx] = in[(size_t)(r0 + r) * C + c0 + tx];
  }
  __syncthreads();
#pragma unroll
  for (int i = 0; i < 4; ++i) {
    int c = tg * 4 + i;
    out[(size_t)(c0 + c) * R + r0 + tx] = f2bf(tile[tx][c]);
  }
}

// ------------------------------ GEMM -------------------------------------
// C[m][n] = sum_k A[m][k]*B[k][n] + bias[n], A bf16 [M][K], Bt bf16 [N][K].
// BK=64, XOR-swizzled LDS staging. MODE 0: q/k/vT outputs via LDS epilogue.
// MODE 1: fp32 out [M][N] direct.
template <int MODE>
__global__ __launch_bounds__(256) void gemm_bt_kernel(
    const short* __restrict__ A, const short* __restrict__ Bt,
    const float* __restrict__ bias, float* __restrict__ outf,
    short* __restrict__ oq, short* __restrict__ ok, short* __restrict__ ovt,
    int M, int N, int K) {
  __shared__ short lds[(MODE == 0) ? 17408 : 16384];
  short* As = lds;            // [128 rows][64 shorts] seg-swizzled
  short* Bs = lds + 8192;
  const int m0 = blockIdx.y * 128, n0 = blockIdx.x * 128;
  const int lane = threadIdx.x & 63, wave = threadIdx.x >> 6;
  const int quad = lane >> 4, l16 = lane & 15;
  const int wm = (wave >> 1) * 64, wn = (wave & 1) * 64;

  // staging: wave covers rows [wave*32, +32); per gld: 8 rows x 8 segs of 16B
  const int row_off = lane >> 3;                 // 0..7
  const int segsw = ((lane & 7) ^ row_off) * 8;  // XOR-swizzled global seg
  const short* Ag = A + (size_t)(m0 + wave * 32 + row_off) * K + segsw;
  const short* Bg = Bt + (size_t)(n0 + wave * 32 + row_off) * K + segsw;

  f32x4 acc[4][4] = {};

  for (int k0 = 0; k0 < K; k0 += 64) {
#pragma unroll
    for (int g = 0; g < 4; ++g) {
      gld_lds16(Ag + (size_t)(g * 8) * K + k0, &As[(wave * 32 + g * 8) * 64]);
      gld_lds16(Bg + (size_t)(g * 8) * K + k0, &Bs[(wave * 32 + g * 8) * 64]);
    }
    __syncthreads();
#pragma unroll
    for (int kh = 0; kh < 2; ++kh) {
      short8 a[4], b[4];
#pragma unroll
      for (int t = 0; t < 4; ++t) {
        const int R = wm + t * 16 + l16;
        a[t] = *(const short8*)&As[R * 64 + (((kh * 4 + quad) ^ (R & 7)) * 8)];
      }
#pragma unroll
      for (int t = 0; t < 4; ++t) {
        const int R = wn + t * 16 + l16;
        b[t] = *(const short8*)&Bs[R * 64 + (((kh * 4 + quad) ^ (R & 7)) * 8)];
      }
#pragma unroll
      for (int mt = 0; mt < 4; ++mt)
#pragma unroll
        for (int nt = 0; nt < 4; ++nt)
          acc[mt][nt] = __builtin_amdgcn_mfma_f32_16x16x32_bf16(
              a[mt], b[nt], acc[mt][nt], 0, 0, 0);
    }
    __syncthreads();
  }

  float bv[4];
#pragma unroll
  for (int nt = 0; nt < 4; ++nt) bv[nt] = bias[n0 + wn + nt * 16 + l16];

  if (MODE == 1) {
#pragma unroll
    for (int mt = 0; mt < 4; ++mt)
#pragma unroll
      for (int nt = 0; nt < 4; ++nt) {
        const int n = n0 + wn + nt * 16 + l16;
#pragma unroll
        for (int r = 0; r < 4; ++r) {
          const int m = m0 + wm + mt * 16 + quad * 4 + r;
          outf[(size_t)m * N + n] = acc[mt][nt][r] + bv[nt];
        }
      }
  } else {
    // ---- LDS epilogue: q/k row-major, v transposed; stride 136 shorts ----
    const int sec = n0 >> 10;  // 0=q 1=k 2=v (uniform per block)
    short* Cs = lds;           // 128 x 136 shorts = 34816 B
    const float scale = (sec == 0) ? 0.18033688f : 1.0f;  // log2e/8 into q
#pragma unroll
    for (int mt = 0; mt < 4; ++mt)
#pragma unroll
      for (int nt = 0; nt < 4; ++nt) {
        const int col = wn + nt * 16 + l16;
#pragma unroll
        for (int r = 0; r < 4; ++r) {
          const int row = wm + mt * 16 + quad * 4 + r;
          const short h = f2bf((acc[mt][nt][r] + bv[nt]) * scale);
          if (sec == 2) Cs[col * 136 + row] = h;
          else          Cs[row * 136 + col] = h;
        }
      }
    __syncthreads();

    const int tid = threadIdx.x;
    const int rw = tid >> 1, half = tid & 1;
    const int h0 = (n0 & 1023) >> 6;
    const short* sp = &Cs[rw * 136 + half * 64];
    if (sec < 2) {
      short* dst = (sec == 0) ? oq : ok;
      const int m = m0 + rw, b_ = m >> 11, tt = m & 2047;
      short* gp = dst + ((size_t)(b_ * 16 + h0 + half) * 2048 + tt) * 64;
#pragma unroll
      for (int i = 0; i < 8; ++i) ((short8*)gp)[i] = ((const short8*)sp)[i];
    } else {
      const int b_ = m0 >> 11, t0 = m0 & 2047;
      const int bh = b_ * 16 + h0 + (rw >> 6), d = rw & 63;
      short* gp = ovt + ((size_t)bh * 64 + d) * 2048 + t0 + half * 64;
#pragma unroll
      for (int i = 0; i < 8; ++i) ((short8*)gp)[i] = ((const short8*)sp)[i];
    }
  }
}

// --------------------------- flash attention -----------------------------
// Block: 128 q-rows (4 waves x 32) of one bh. Chunks of 64 K-rows staged to
// LDS cooperatively. Per chunk: K/V fragments read once, reused across both
// 16-row subtiles; P for both subtiles written before one lgkm wait.
// p = 2^s (scale folded in q); mask only near-diagonal; row-sums via ones-B
// MFMA. blockIdx: bh = g>>4, slot = g&15, jb via m[s]+m[s^8]=15 pairing.
__global__ __launch_bounds__(256, 4) void attn_kernel(
    const short* __restrict__ q, const short* __restrict__ k,
    const short* __restrict__ vt, short* __restrict__ y) {
  __shared__ short Ks[64 * 64];
  __shared__ short Vs[64 * 64];
  __shared__ short Ps[4][32 * 72];
  const int lane = threadIdx.x & 63, wave = threadIdx.x >> 6;
  const int quad = lane >> 4, l16 = lane & 15;
  const int g = blockIdx.x;
  const int bh = g >> 4;
  const int slot = g & 15;
  const int jb = (slot < 8) ? (15 - 2 * slot) : (2 * slot - 16);
  const int b_ = bh >> 4, h = bh & 15;
  const int q0 = jb * 128 + wave * 32;   // wave's 32 q-rows

  const short* qbh = q + (size_t)bh * 2048 * 64;
  const short* kbh = k + (size_t)bh * 2048 * 64;
  const short* vbh = vt + (size_t)bh * 64 * 2048;
  short* Pw = Ps[wave];

  short8 qf[2][2];
#pragma unroll
  for (int s = 0; s < 2; ++s) {
    qf[s][0] = *(const short8*)&qbh[(q0 + s * 16 + l16) * 64 + quad * 8];
    qf[s][1] = *(const short8*)&qbh[(q0 + s * 16 + l16) * 64 + 32 + quad * 8];
  }

  short8 ones;
#pragma unroll
  for (int i = 0; i < 8; ++i) ones[i] = (short)0x3F80;  // bf16 1.0

  f32x4 O[2][4] = {};
  f32x4 lacc[2] = {};

  const int srow = lane >> 3;
  const int scol = ((lane & 7) ^ srow) * 8;
  const int r0s = wave * 16;
  const int sw = l16 & 7;
  const int nch = 2 * jb + 2;

#pragma unroll 1
  for (int c = 0; c < nch; ++c) {
    const int kt0 = c * 64;
    gld_lds16(kbh + (size_t)(kt0 + r0s + srow) * 64 + scol, &Ks[r0s * 64]);
    gld_lds16(kbh + (size_t)(kt0 + r0s + 8 + srow) * 64 + scol, &Ks[(r0s + 8) * 64]);
    gld_lds16(vbh + (size_t)(r0s + srow) * 2048 + kt0 + scol, &Vs[r0s * 64]);
    gld_lds16(vbh + (size_t)(r0s + 8 + srow) * 2048 + kt0 + scol, &Vs[(r0s + 8) * 64]);
    __syncthreads();

    if (kt0 < q0 + 32) {   // both subtiles active (64-aligned kt0)
      // ---- QK^T: K frags read once, used by both subtiles ----
      f32x4 sc[2][4];
#pragma unroll
      for (int cf = 0; cf < 4; ++cf) {
        const int row = cf * 16 + l16;
        const short8 kfa = *(const short8*)&Ks[row * 64 + ((quad ^ sw) * 8)];
        const short8 kfb = *(const short8*)&Ks[row * 64 + (((quad + 4) ^ sw) * 8)];
#pragma unroll
        for (int s = 0; s < 2; ++s) {
          f32x4 z = {};
          z = __builtin_amdgcn_mfma_f32_16x16x32_bf16(qf[s][0], kfa, z, 0, 0, 0);
          z = __builtin_amdgcn_mfma_f32_16x16x32_bf16(qf[s][1], kfb, z, 0, 0, 0);
          sc[s][cf] = z;
        }
      }

      // ---- p = 2^s, mask only near diagonal; both subtiles to LDS ----
      if (kt0 + 64 > q0) {
#pragma unroll
        for (int s = 0; s < 2; ++s) {
          const int qs = q0 + s * 16;
#pragma unroll
          for (int cf = 0; cf < 4; ++cf) {
            const int col = kt0 + cf * 16 + l16;
#pragma unroll
            for (int r = 0; r < 4; ++r) {
              const int rowg = qs + quad * 4 + r;
              float e = exp2_fast(sc[s][cf][r]);
              e = (col > rowg) ? 0.f : e;
              Pw[(s * 16 + quad * 4 + r) * 72 + cf * 16 + l16] = f2bf(e);
            }
          }
        }
      } else {
#pragma unroll
        for (int s = 0; s < 2; ++s)
#pragma unroll
          for (int cf = 0; cf < 4; ++cf)
#pragma unroll
            for (int r = 0; r < 4; ++r)
              Pw[(s * 16 + quad * 4 + r) * 72 + cf * 16 + l16] =
                  f2bf(exp2_fast(sc[s][cf][r]));
      }
      asm volatile("s_waitcnt lgkmcnt(0)" ::: "memory");

      short8 pf[2][2];
#pragma unroll
      for (int s = 0; s < 2; ++s) {
        pf[s][0] = *(const short8*)&Pw[(s * 16 + l16) * 72 + quad * 8];
        pf[s][1] = *(const short8*)&Pw[(s * 16 + l16) * 72 + 32 + quad * 8];
      }

#pragma unroll
      for (int s = 0; s < 2; ++s) {
        lacc[s] = __builtin_amdgcn_mfma_f32_16x16x32_bf16(pf[s][0], ones, lacc[s], 0, 0, 0);
        lacc[s] = __builtin_amdgcn_mfma_f32_16x16x32_bf16(pf[s][1], ones, lacc[s], 0, 0, 0);
      }

      // ---- PV: V frags read once, used by both subtiles ----
#pragma unroll
      for (int dt = 0; dt < 4; ++dt) {
        const int d = dt * 16 + l16;
        const short8 vf0 = *(const short8*)&Vs[d * 64 + ((quad ^ sw) * 8)];
        const short8 vf1 = *(const short8*)&Vs[d * 64 + (((quad + 4) ^ sw) * 8)];
#pragma unroll
        for (int s = 0; s < 2; ++s) {
          O[s][dt] = __builtin_amdgcn_mfma_f32_16x16x32_bf16(pf[s][0], vf0, O[s][dt], 0, 0, 0);
          O[s][dt] = __builtin_amdgcn_mfma_f32_16x16x32_bf16(pf[s][1], vf1, O[s][dt], 0, 0, 0);
        }
      }
    }
    __syncthreads();
  }

#pragma unroll
  for (int s = 0; s < 2; ++s) {
    float inv[4];
#pragma unroll
    for (int r = 0; r < 4; ++r) inv[r] = 1.0f / lacc[s][r];
#pragma unroll
    for (int dt = 0; dt < 4; ++dt) {
      const int d = dt * 16 + l16;
#pragma unroll
      for (int r = 0; r < 4; ++r) {
        const int t_ = q0 + s * 16 + quad * 4 + r;
        y[((size_t)b_ * 2048 + t_) * 1024 + h * 64 + d] = f2bf(O[s][dt][r] * inv[r]);
      }
    }
  }
}

// -------------------------------------------------------------------------
extern "C" void kernel_launch(void* const* d_in, const int* in_sizes, int n_in,
                              void* d_out, int out_size, void* d_ws, size_t ws_size,
                              hipStream_t stream) {
  const float* x      = (const float*)d_in[0];
  const float* w_attn = (const float*)d_in[1];
  const float* b_attn = (const float*)d_in[2];
  const float* w_proj = (const float*)d_in[3];
  const float* b_proj = (const float*)d_in[4];
  float* out = (float*)d_out;

  short* xb  = (short*)d_ws;                    // [8192][1024]
  short* wTa = xb + (size_t)8192 * 1024;        // [3072][1024]
  short* wTp = wTa + (size_t)3072 * 1024;       // [1024][1024]
  short* qb  = wTp + (size_t)1024 * 1024;       // [64][2048][64]
  short* kb  = qb + (size_t)64 * 2048 * 64;     // [64][2048][64]
  short* vtb = kb + (size_t)64 * 2048 * 64;     // [64][64][2048]
  short* yb  = vtb + (size_t)64 * 2048 * 64;    // [8192][1024]

  cast_bf16_kernel<<<8192, 256, 0, stream>>>(x, xb, 8192 * 1024 / 4);
  transpose_cast_kernel<<<dim3(96, 32), 256, 0, stream>>>(w_attn, wTa, 1024, 3072);
  transpose_cast_kernel<<<dim3(32, 32), 256, 0, stream>>>(w_proj, wTp, 1024, 1024);

  gemm_bt_kernel<0><<<dim3(24, 64), 256, 0, stream>>>(
      xb, wTa, b_attn, nullptr, qb, kb, vtb, 8192, 3072, 1024);

  attn_kernel<<<1024, 256, 0, stream>>>(qb, kb, vtb, yb);

  gemm_bt_kernel<1><<<dim3(8, 64), 256, 0, stream>>>(
      yb, wTp, b_proj, out, nullptr, nullptr, nullptr, 8192, 1024, 1024);
}

// Round 7
// 259.945 us; speedup vs baseline: 1.1026x; 1.1026x over previous
//
#include <hip/hip_runtime.h>
#include <cmath>

// Round 7: revert attn to round-5 version (round-6's 128-row blocks dropped
// residency 24->16 waves/CU and regressed 70->94us; latency-hiding-bound).
// GEMM: two-pass MODE-0 epilogue reusing the As/Bs LDS region (32KB total,
// was 34.8KB) -> 5 blocks/CU instead of 4 for the latency-bound K-loop.
// B=4 T=2048 C=1024 H=16 hd=64.

typedef short short8 __attribute__((ext_vector_type(8)));
typedef short short4v __attribute__((ext_vector_type(4)));
typedef float f32x4 __attribute__((ext_vector_type(4)));

__device__ __forceinline__ short f2bf(float f) {
  unsigned u = __builtin_bit_cast(unsigned, f);
  u = (u + 0x7fffu + ((u >> 16) & 1u)) >> 16;   // RNE; inputs are finite
  return (short)u;
}

__device__ __forceinline__ float exp2_fast(float x) {
  float r;
  asm("v_exp_f32 %0, %1" : "=v"(r) : "v"(x));
  return r;
}

__device__ __forceinline__ void gld_lds16(const void* g, void* l) {
  __builtin_amdgcn_global_load_lds(
      (__attribute__((address_space(1))) void*)g,
      (__attribute__((address_space(3))) void*)l,
      16, 0, 0);
}

// ---------------- cast fp32 -> bf16 bits (4 elems/thread) ----------------
__global__ void cast_bf16_kernel(const float* __restrict__ in,
                                 short* __restrict__ out, int n4) {
  int i = blockIdx.x * blockDim.x + threadIdx.x;
  if (i < n4) {
    const float4 v = ((const float4*)in)[i];
    short4v o;
    o.x = f2bf(v.x); o.y = f2bf(v.y); o.z = f2bf(v.z); o.w = f2bf(v.w);
    ((short4v*)out)[i] = o;
  }
}

// ------------- transpose+cast: fp32 [R][C] -> bf16 [C][R] ----------------
__global__ void transpose_cast_kernel(const float* __restrict__ in,
                                      short* __restrict__ out, int R, int C) {
  __shared__ float tile[32][33];
  int c0 = blockIdx.x * 32, r0 = blockIdx.y * 32;
  int tx = threadIdx.x & 31, tg = threadIdx.x >> 5;
#pragma unroll
  for (int i = 0; i < 4; ++i) {
    int r = tg * 4 + i;
    tile[r][tx] = in[(size_t)(r0 + r) * C + c0 + tx];
  }
  __syncthreads();
#pragma unroll
  for (int i = 0; i < 4; ++i) {
    int c = tg * 4 + i;
    out[(size_t)(c0 + c) * R + r0 + tx] = f2bf(tile[tx][c]);
  }
}

// ------------------------------ GEMM -------------------------------------
// C[m][n] = sum_k A[m][k]*B[k][n] + bias[n], A bf16 [M][K], Bt bf16 [N][K].
// BK=64, XOR-swizzled LDS staging. MODE 0: q/k/vT via two-pass LDS epilogue
// reusing As/Bs (keeps LDS at 32KB). MODE 1: fp32 out [M][N] direct.
template <int MODE>
__global__ __launch_bounds__(256) void gemm_bt_kernel(
    const short* __restrict__ A, const short* __restrict__ Bt,
    const float* __restrict__ bias, float* __restrict__ outf,
    short* __restrict__ oq, short* __restrict__ ok, short* __restrict__ ovt,
    int M, int N, int K) {
  __shared__ short lds[16384];  // As[128][64] + Bs[128][64] = 32KB
  short* As = lds;
  short* Bs = lds + 8192;
  const int m0 = blockIdx.y * 128, n0 = blockIdx.x * 128;
  const int lane = threadIdx.x & 63, wave = threadIdx.x >> 6;
  const int quad = lane >> 4, l16 = lane & 15;
  const int wm = (wave >> 1) * 64, wn = (wave & 1) * 64;

  // staging: wave covers rows [wave*32, +32); per gld: 8 rows x 8 segs of 16B
  const int row_off = lane >> 3;                 // 0..7
  const int segsw = ((lane & 7) ^ row_off) * 8;  // XOR-swizzled global seg
  const short* Ag = A + (size_t)(m0 + wave * 32 + row_off) * K + segsw;
  const short* Bg = Bt + (size_t)(n0 + wave * 32 + row_off) * K + segsw;

  f32x4 acc[4][4] = {};

  for (int k0 = 0; k0 < K; k0 += 64) {
#pragma unroll
    for (int g = 0; g < 4; ++g) {
      gld_lds16(Ag + (size_t)(g * 8) * K + k0, &As[(wave * 32 + g * 8) * 64]);
      gld_lds16(Bg + (size_t)(g * 8) * K + k0, &Bs[(wave * 32 + g * 8) * 64]);
    }
    __syncthreads();
#pragma unroll
    for (int kh = 0; kh < 2; ++kh) {
      short8 a[4], b[4];
#pragma unroll
      for (int t = 0; t < 4; ++t) {
        const int R = wm + t * 16 + l16;
        a[t] = *(const short8*)&As[R * 64 + (((kh * 4 + quad) ^ (R & 7)) * 8)];
      }
#pragma unroll
      for (int t = 0; t < 4; ++t) {
        const int R = wn + t * 16 + l16;
        b[t] = *(const short8*)&Bs[R * 64 + (((kh * 4 + quad) ^ (R & 7)) * 8)];
      }
#pragma unroll
      for (int mt = 0; mt < 4; ++mt)
#pragma unroll
        for (int nt = 0; nt < 4; ++nt)
          acc[mt][nt] = __builtin_amdgcn_mfma_f32_16x16x32_bf16(
              a[mt], b[nt], acc[mt][nt], 0, 0, 0);
    }
    __syncthreads();
  }

  float bv[4];
#pragma unroll
  for (int nt = 0; nt < 4; ++nt) bv[nt] = bias[n0 + wn + nt * 16 + l16];

  if (MODE == 1) {
#pragma unroll
    for (int mt = 0; mt < 4; ++mt)
#pragma unroll
      for (int nt = 0; nt < 4; ++nt) {
        const int n = n0 + wn + nt * 16 + l16;
#pragma unroll
        for (int r = 0; r < 4; ++r) {
          const int m = m0 + wm + mt * 16 + quad * 4 + r;
          outf[(size_t)m * N + n] = acc[mt][nt][r] + bv[nt];
        }
      }
  } else {
    // ---- two-pass LDS epilogue in the As/Bs region (<=16384 shorts) ----
    // pass p handles C rows [p*64, p*64+64) (owned by waves 2p, 2p+1).
    // q/k: Cs[64][136] row-major. v: Cs[128][72] transposed (col-major).
    const int sec = n0 >> 10;  // 0=q 1=k 2=v (uniform per block)
    const int h0 = (n0 & 1023) >> 6;
    const float scale = (sec == 0) ? 0.18033688f : 1.0f;  // log2e/8 into q
    short* Cs = lds;
    const int tid = threadIdx.x;
#pragma unroll 1
    for (int p = 0; p < 2; ++p) {
      if ((wave >> 1) == p) {
#pragma unroll
        for (int mt = 0; mt < 4; ++mt)
#pragma unroll
          for (int nt = 0; nt < 4; ++nt) {
            const int col = wn + nt * 16 + l16;
#pragma unroll
            for (int r = 0; r < 4; ++r) {
              const int row = mt * 16 + quad * 4 + r;  // local 0..63
              const short hv = f2bf((acc[mt][nt][r] + bv[nt]) * scale);
              if (sec == 2) Cs[col * 72 + row] = hv;
              else          Cs[row * 136 + col] = hv;
            }
          }
      }
      __syncthreads();
      if (sec < 2) {
        short* dst = (sec == 0) ? oq : ok;
        const int rw = tid >> 2, seg = tid & 3;
        const int m = m0 + p * 64 + rw, b_ = m >> 11, tt = m & 2047;
        const short* sp = &Cs[rw * 136 + seg * 32];
        short* gp = dst +
            ((size_t)(b_ * 16 + h0 + (seg >> 1)) * 2048 + tt) * 64 +
            (seg & 1) * 32;
#pragma unroll
        for (int i = 0; i < 4; ++i) ((short8*)gp)[i] = ((const short8*)sp)[i];
      } else {
        const int b_ = m0 >> 11, t0 = m0 & 2047;
        const int col = tid >> 1, rh = tid & 1;
        const int bh = b_ * 16 + h0 + (col >> 6), d = col & 63;
        const short* sp = &Cs[col * 72 + rh * 32];
        short* gp = ovt + ((size_t)bh * 64 + d) * 2048 + t0 + p * 64 + rh * 32;
#pragma unroll
        for (int i = 0; i < 4; ++i) ((short8*)gp)[i] = ((const short8*)sp)[i];
      }
      __syncthreads();
    }
  }
}

// --------------------------- flash attention -----------------------------
// (round-5 version) Block: 64 q-rows (4 waves x 16) of one bh. Chunks of 64
// K-rows staged to LDS cooperatively (async, swizzled). p = 2^s (scale
// folded in q); mask only on diagonal chunk; row-sums via ones-B MFMA.
// 25.6KB LDS -> 6 blocks/CU = 24 waves/CU (latency-hiding is the binding
// constraint here; 128-row/4-block variant measured slower).
__global__ __launch_bounds__(256, 6) void attn_kernel(
    const short* __restrict__ q, const short* __restrict__ k,
    const short* __restrict__ vt, short* __restrict__ y) {
  __shared__ short Ks[64 * 64];
  __shared__ short Vs[64 * 64];
  __shared__ short Ps[4][16 * 72];
  const int lane = threadIdx.x & 63, wave = threadIdx.x >> 6;
  const int quad = lane >> 4, l16 = lane & 15;
  const int g = blockIdx.x;
  const int bh = g & 63;
  const int j = 31 - (g >> 6);  // big blocks dispatched first
  const int b_ = bh >> 4, h = bh & 15;
  const int q0 = j * 64 + wave * 16;

  const short* qbh = q + (size_t)bh * 2048 * 64;
  const short* kbh = k + (size_t)bh * 2048 * 64;
  const short* vbh = vt + (size_t)bh * 64 * 2048;
  short* Pw = Ps[wave];

  const short8 qf0 = *(const short8*)&qbh[(q0 + l16) * 64 + quad * 8];
  const short8 qf1 = *(const short8*)&qbh[(q0 + l16) * 64 + 32 + quad * 8];

  short8 ones;
#pragma unroll
  for (int i = 0; i < 8; ++i) ones[i] = (short)0x3F80;  // bf16 1.0

  f32x4 O[4] = {};
  f32x4 lacc = {};

  const int srow = lane >> 3;
  const int scol = ((lane & 7) ^ srow) * 8;
  const int r0s = wave * 16;

#pragma unroll 1
  for (int c = 0; c <= j; ++c) {
    const int kt0 = c * 64;
    gld_lds16(kbh + (size_t)(kt0 + r0s + srow) * 64 + scol, &Ks[r0s * 64]);
    gld_lds16(kbh + (size_t)(kt0 + r0s + 8 + srow) * 64 + scol, &Ks[(r0s + 8) * 64]);
    gld_lds16(vbh + (size_t)(r0s + srow) * 2048 + kt0 + scol, &Vs[r0s * 64]);
    gld_lds16(vbh + (size_t)(r0s + 8 + srow) * 2048 + kt0 + scol, &Vs[(r0s + 8) * 64]);
    __syncthreads();

    const int sw = l16 & 7;
    f32x4 sc4[4];
#pragma unroll
    for (int cf = 0; cf < 4; ++cf) {
      const int row = cf * 16 + l16;
      const short8 kfa = *(const short8*)&Ks[row * 64 + ((quad ^ sw) * 8)];
      const short8 kfb = *(const short8*)&Ks[row * 64 + (((quad + 4) ^ sw) * 8)];
      f32x4 z = {};
      z = __builtin_amdgcn_mfma_f32_16x16x32_bf16(qf0, kfa, z, 0, 0, 0);
      z = __builtin_amdgcn_mfma_f32_16x16x32_bf16(qf1, kfb, z, 0, 0, 0);
      sc4[cf] = z;
    }

    if (c == j) {
#pragma unroll
      for (int cf = 0; cf < 4; ++cf) {
        const int col = kt0 + cf * 16 + l16;
#pragma unroll
        for (int r = 0; r < 4; ++r) {
          const int rowg = q0 + quad * 4 + r;
          float e = exp2_fast(sc4[cf][r]);
          e = (col > rowg) ? 0.f : e;
          Pw[(quad * 4 + r) * 72 + cf * 16 + l16] = f2bf(e);
        }
      }
    } else {
#pragma unroll
      for (int cf = 0; cf < 4; ++cf)
#pragma unroll
        for (int r = 0; r < 4; ++r)
          Pw[(quad * 4 + r) * 72 + cf * 16 + l16] = f2bf(exp2_fast(sc4[cf][r]));
    }
    asm volatile("s_waitcnt lgkmcnt(0)" ::: "memory");
    const short8 pf0 = *(const short8*)&Pw[l16 * 72 + quad * 8];
    const short8 pf1 = *(const short8*)&Pw[l16 * 72 + 32 + quad * 8];

    lacc = __builtin_amdgcn_mfma_f32_16x16x32_bf16(pf0, ones, lacc, 0, 0, 0);
    lacc = __builtin_amdgcn_mfma_f32_16x16x32_bf16(pf1, ones, lacc, 0, 0, 0);

#pragma unroll
    for (int dt = 0; dt < 4; ++dt) {
      const int d = dt * 16 + l16;
      const short8 vf0 = *(const short8*)&Vs[d * 64 + ((quad ^ sw) * 8)];
      const short8 vf1 = *(const short8*)&Vs[d * 64 + (((quad + 4) ^ sw) * 8)];
      O[dt] = __builtin_amdgcn_mfma_f32_16x16x32_bf16(pf0, vf0, O[dt], 0, 0, 0);
      O[dt] = __builtin_amdgcn_mfma_f32_16x16x32_bf16(pf1, vf1, O[dt], 0, 0, 0);
    }
    __syncthreads();
  }

  float inv[4];
#pragma unroll
  for (int r = 0; r < 4; ++r) inv[r] = 1.0f / lacc[r];
#pragma unroll
  for (int dt = 0; dt < 4; ++dt) {
    const int d = dt * 16 + l16;
#pragma unroll
    for (int r = 0; r < 4; ++r) {
      const int t_ = q0 + quad * 4 + r;
      y[((size_t)b_ * 2048 + t_) * 1024 + h * 64 + d] = f2bf(O[dt][r] * inv[r]);
    }
  }
}

// -------------------------------------------------------------------------
extern "C" void kernel_launch(void* const* d_in, const int* in_sizes, int n_in,
                              void* d_out, int out_size, void* d_ws, size_t ws_size,
                              hipStream_t stream) {
  const float* x      = (const float*)d_in[0];
  const float* w_attn = (const float*)d_in[1];
  const float* b_attn = (const float*)d_in[2];
  const float* w_proj = (const float*)d_in[3];
  const float* b_proj = (const float*)d_in[4];
  float* out = (float*)d_out;

  short* xb  = (short*)d_ws;                    // [8192][1024]
  short* wTa = xb + (size_t)8192 * 1024;        // [3072][1024]
  short* wTp = wTa + (size_t)3072 * 1024;       // [1024][1024]
  short* qb  = wTp + (size_t)1024 * 1024;       // [64][2048][64]
  short* kb  = qb + (size_t)64 * 2048 * 64;     // [64][2048][64]
  short* vtb = kb + (size_t)64 * 2048 * 64;     // [64][64][2048]
  short* yb  = vtb + (size_t)64 * 2048 * 64;    // [8192][1024]

  cast_bf16_kernel<<<8192, 256, 0, stream>>>(x, xb, 8192 * 1024 / 4);
  transpose_cast_kernel<<<dim3(96, 32), 256, 0, stream>>>(w_attn, wTa, 1024, 3072);
  transpose_cast_kernel<<<dim3(32, 32), 256, 0, stream>>>(w_proj, wTp, 1024, 1024);

  gemm_bt_kernel<0><<<dim3(24, 64), 256, 0, stream>>>(
      xb, wTa, b_attn, nullptr, qb, kb, vtb, 8192, 3072, 1024);

  attn_kernel<<<2048, 256, 0, stream>>>(qb, kb, vtb, yb);

  gemm_bt_kernel<1><<<dim3(8, 64), 256, 0, stream>>>(
      yb, wTp, b_proj, out, nullptr, nullptr, nullptr, 8192, 1024, 1024);
}